// Round 1
// baseline (588.222 us; speedup 1.0000x reference)
//
#include <hip/hip_runtime.h>
#include <math.h>

// Problem constants (from setup_inputs): B=16384 rows, C=4096 cols, NBINS=1000.
constexpr int BROWS = 16384;
constexpr int CCOLS = 4096;
constexpr int BLOCK = 256;            // 4 waves; 16 floats/thread covers a row
constexpr float F_EPS      = 1e-7f;
constexpr float F_1M_EPS   = 1.0f - 1e-7f;
constexpr float LOG_EPS    = -16.118095651f;   // log(1e-7)
constexpr float LOG_1M_EPS = -1.0000000e-7f;   // log(1 - 1e-7)

__device__ __forceinline__ float wave_reduce_sum(float v) {
#pragma unroll
    for (int m = 32; m > 0; m >>= 1) v += __shfl_xor(v, m, 64);
    return v;
}
__device__ __forceinline__ float wave_reduce_max(float v) {
#pragma unroll
    for (int m = 32; m > 0; m >>= 1) v = fmaxf(v, __shfl_xor(v, m, 64));
    return v;
}

// y*log(clip(p)) + (1-y)*log1p(-clip(p))   (i.e. MINUS the bce term)
__device__ __forceinline__ float nbce_elem(float x, float y, float off) {
    float z = x - off;                 // log-softmax value
    float p = __expf(z);
    p = fminf(fmaxf(p, F_EPS), F_1M_EPS);
    // log of the clipped p: log is monotone, so clamp z directly (cheaper + exact-enough)
    float logp  = fminf(fmaxf(z, LOG_EPS), LOG_1M_EPS);
    // log1p(-p): exact via Sterbenz for p>=0.5; abs err < 2^-24 for p<0.5
    float log1mp = __logf(1.0f - p);
    return fmaf(y, logp, (1.0f - y) * log1mp);
}

__global__ void zero_acc_kernel(double* acc) { *acc = 0.0; }

__global__ void __launch_bounds__(BLOCK)
wce_main_kernel(const float* __restrict__ y_pred,
                const float* __restrict__ y_true,
                const float* __restrict__ weights,
                const int*   __restrict__ cond,
                double* __restrict__ acc)
{
    __shared__ float s_max[4];
    __shared__ float s_sum[4];
    __shared__ float s_bce[4];

    const int row = blockIdx.x;
    const int tid = threadIdx.x;
    const int wave = tid >> 6;
    const int lane = tid & 63;
    const size_t base = (size_t)row * CCOLS;

    const float4* yp4 = (const float4*)(y_pred + base);
    const float4* yt4 = (const float4*)(y_true + base);

    // ---- pass 1: load row into registers (16 floats/thread), local max ----
    float4 v[4];
    float lmax = -3.4e38f;
#pragma unroll
    for (int i = 0; i < 4; ++i) {
        v[i] = yp4[tid + BLOCK * i];
        lmax = fmaxf(lmax, fmaxf(fmaxf(v[i].x, v[i].y), fmaxf(v[i].z, v[i].w)));
    }
    lmax = wave_reduce_max(lmax);
    if (lane == 0) s_max[wave] = lmax;
    __syncthreads();
    const float m = fmaxf(fmaxf(s_max[0], s_max[1]), fmaxf(s_max[2], s_max[3]));

    // ---- pass 2: sum of exp(x - m) from registers ----
    float lsum = 0.0f;
#pragma unroll
    for (int i = 0; i < 4; ++i) {
        lsum += __expf(v[i].x - m) + __expf(v[i].y - m)
              + __expf(v[i].z - m) + __expf(v[i].w - m);
    }
    lsum = wave_reduce_sum(lsum);
    if (lane == 0) s_sum[wave] = lsum;
    __syncthreads();
    const float s   = (s_sum[0] + s_sum[1]) + (s_sum[2] + s_sum[3]);
    const float off = m + __logf(s);        // log-softmax offset: z = x - off

    // ---- pass 3: stream y_true, weighted clipped BCE ----
    const float w = weights[cond[row]];     // broadcast load, L2-resident

    float nb = 0.0f;
#pragma unroll
    for (int i = 0; i < 4; ++i) {
        float4 t = yt4[tid + BLOCK * i];
        nb += nbce_elem(v[i].x, t.x, off);
        nb += nbce_elem(v[i].y, t.y, off);
        nb += nbce_elem(v[i].z, t.z, off);
        nb += nbce_elem(v[i].w, t.w, off);
    }
    nb = wave_reduce_sum(nb);
    if (lane == 0) s_bce[wave] = nb;
    __syncthreads();
    if (tid == 0) {
        const float row_nbce = (s_bce[0] + s_bce[1]) + (s_bce[2] + s_bce[3]);
        // bce = -row_nbce; weighted contribution:
        atomicAdd(acc, (double)(-w * row_nbce));
    }
}

__global__ void finalize_kernel(const double* __restrict__ acc, float* __restrict__ out) {
    out[0] = (float)(acc[0] / ((double)BROWS * (double)CCOLS));
}

extern "C" void kernel_launch(void* const* d_in, const int* in_sizes, int n_in,
                              void* d_out, int out_size, void* d_ws, size_t ws_size,
                              hipStream_t stream) {
    const float* y_pred  = (const float*)d_in[0];
    const float* y_true  = (const float*)d_in[1];
    const float* weights = (const float*)d_in[2];
    const int*   cond    = (const int*)d_in[3];
    float*  out = (float*)d_out;
    double* acc = (double*)d_ws;

    zero_acc_kernel<<<1, 1, 0, stream>>>(acc);
    wce_main_kernel<<<BROWS, BLOCK, 0, stream>>>(y_pred, y_true, weights, cond, acc);
    finalize_kernel<<<1, 1, 0, stream>>>(acc, out);
}

// Round 2
// 499.745 us; speedup vs baseline: 1.1770x; 1.1770x over previous
//
#include <hip/hip_runtime.h>
#include <math.h>

// Problem constants (from setup_inputs): B=16384 rows, C=4096 cols, NBINS=1000.
constexpr int BROWS = 16384;
constexpr int CCOLS = 4096;
constexpr int BLOCK = 256;            // 4 waves; 16 floats/thread covers a row
constexpr float F_EPS      = 1e-7f;
constexpr float F_1M_EPS   = 1.0f - 1e-7f;
constexpr float LOG_EPS    = -16.118095651f;   // log(1e-7)
constexpr float LOG_1M_EPS = -1.0000000e-7f;   // log(1 - 1e-7)

__device__ __forceinline__ float wave_reduce_sum(float v) {
#pragma unroll
    for (int m = 32; m > 0; m >>= 1) v += __shfl_xor(v, m, 64);
    return v;
}
__device__ __forceinline__ float wave_reduce_max(float v) {
#pragma unroll
    for (int m = 32; m > 0; m >>= 1) v = fmaxf(v, __shfl_xor(v, m, 64));
    return v;
}
__device__ __forceinline__ double wave_reduce_sum_d(double v) {
#pragma unroll
    for (int m = 32; m > 0; m >>= 1) v += __shfl_xor(v, m, 64);
    return v;
}

// y*log(clip(p)) + (1-y)*log1p(-clip(p))   (MINUS the bce term)
__device__ __forceinline__ float nbce_elem(float x, float y, float off) {
    float z = x - off;                 // log-softmax value
    float p = __expf(z);
    p = fminf(fmaxf(p, F_EPS), F_1M_EPS);
    // log of clipped p: log is monotone -> clamp z directly
    float logp   = fminf(fmaxf(z, LOG_EPS), LOG_1M_EPS);
    // log1p(-p): exact via Sterbenz for p>=0.5; abs err < 2^-24 for p<0.5
    float log1mp = __logf(1.0f - p);
    return fmaf(y, logp, (1.0f - y) * log1mp);
}

__global__ void __launch_bounds__(BLOCK)
wce_main_kernel(const float* __restrict__ y_pred,
                const float* __restrict__ y_true,
                const float* __restrict__ weights,
                const int*   __restrict__ cond,
                float* __restrict__ partials)   // [BROWS] per-row weighted bce sums
{
    __shared__ float s_max[4];
    __shared__ float s_sum[4];
    __shared__ float s_bce[4];

    const int row  = blockIdx.x;
    const int tid  = threadIdx.x;
    const int wave = tid >> 6;
    const int lane = tid & 63;
    const size_t base = (size_t)row * CCOLS;

    const float4* yp4 = (const float4*)(y_pred + base);
    const float4* yt4 = (const float4*)(y_true + base);

    // ---- issue ALL loads up front: y_pred (used first) then y_true prefetch ----
    float4 v[4];
    float4 t[4];
#pragma unroll
    for (int i = 0; i < 4; ++i) v[i] = yp4[tid + BLOCK * i];
#pragma unroll
    for (int i = 0; i < 4; ++i) t[i] = yt4[tid + BLOCK * i];

    // ---- pass 1: row max (only needs v) ----
    float lmax = -3.4e38f;
#pragma unroll
    for (int i = 0; i < 4; ++i)
        lmax = fmaxf(lmax, fmaxf(fmaxf(v[i].x, v[i].y), fmaxf(v[i].z, v[i].w)));
    lmax = wave_reduce_max(lmax);
    if (lane == 0) s_max[wave] = lmax;
    __syncthreads();
    const float m = fmaxf(fmaxf(s_max[0], s_max[1]), fmaxf(s_max[2], s_max[3]));

    // ---- pass 2: sum exp(x - m) ----
    float lsum = 0.0f;
#pragma unroll
    for (int i = 0; i < 4; ++i) {
        lsum += __expf(v[i].x - m) + __expf(v[i].y - m)
              + __expf(v[i].z - m) + __expf(v[i].w - m);
    }
    lsum = wave_reduce_sum(lsum);
    if (lane == 0) s_sum[wave] = lsum;
    __syncthreads();
    const float s   = (s_sum[0] + s_sum[1]) + (s_sum[2] + s_sum[3]);
    const float off = m + __logf(s);        // log-softmax offset: z = x - off

    // ---- pass 3: weighted clipped BCE from registers ----
    const float w = weights[cond[row]];

    float nb = 0.0f;
#pragma unroll
    for (int i = 0; i < 4; ++i) {
        nb += nbce_elem(v[i].x, t[i].x, off);
        nb += nbce_elem(v[i].y, t[i].y, off);
        nb += nbce_elem(v[i].z, t[i].z, off);
        nb += nbce_elem(v[i].w, t[i].w, off);
    }
    nb = wave_reduce_sum(nb);
    if (lane == 0) s_bce[wave] = nb;
    __syncthreads();
    if (tid == 0) {
        const float row_nbce = (s_bce[0] + s_bce[1]) + (s_bce[2] + s_bce[3]);
        partials[row] = -w * row_nbce;      // positive weighted bce contribution
    }
}

// Reduce BROWS partials (f32) in double, divide, write the scalar loss.
__global__ void __launch_bounds__(256)
wce_reduce_kernel(const float* __restrict__ partials, float* __restrict__ out)
{
    __shared__ double s_part[4];
    const int tid  = threadIdx.x;
    const int wave = tid >> 6;
    const int lane = tid & 63;

    const float4* p4 = (const float4*)partials;
    double s = 0.0;
#pragma unroll
    for (int i = 0; i < BROWS / (256 * 4); ++i) {   // 16 iters: 16384/4 float4s / 256 thr
        float4 p = p4[tid + 256 * i];
        s += (double)p.x + (double)p.y + (double)p.z + (double)p.w;
    }
    s = wave_reduce_sum_d(s);
    if (lane == 0) s_part[wave] = s;
    __syncthreads();
    if (tid == 0) {
        double total = (s_part[0] + s_part[1]) + (s_part[2] + s_part[3]);
        out[0] = (float)(total / ((double)BROWS * (double)CCOLS));
    }
}

extern "C" void kernel_launch(void* const* d_in, const int* in_sizes, int n_in,
                              void* d_out, int out_size, void* d_ws, size_t ws_size,
                              hipStream_t stream) {
    const float* y_pred  = (const float*)d_in[0];
    const float* y_true  = (const float*)d_in[1];
    const float* weights = (const float*)d_in[2];
    const int*   cond    = (const int*)d_in[3];
    float* out      = (float*)d_out;
    float* partials = (float*)d_ws;   // BROWS floats = 64 KB scratch

    wce_main_kernel<<<BROWS, BLOCK, 0, stream>>>(y_pred, y_true, weights, cond, partials);
    wce_reduce_kernel<<<1, 256, 0, stream>>>(partials, out);
}